// Round 1
// baseline (138.445 us; speedup 1.0000x reference)
//
#include <hip/hip_runtime.h>
#include <math.h>

#define NCLS 80
#define BINS 17
#define REGMAX 16
#define NG 32
#define NB 16
#define KTOP 10
#define RAD 2.5f

// ---------- workspace layout (bytes) ----------
// [0,   8)    : float acc[2]   (box_sum, cls_sum)
// [32,  224)  : float npos[3][NB]
// [224, 416)  : float dfln[3][NB]
// [416, 608)  : int   anyp[3][NB]
// [608, 62048): int   fb[3][NB][NG][KTOP]
#define WS_ACC   0
#define WS_NPOS  32
#define WS_DFLN  224
#define WS_ANYP  416
#define WS_FB    608
#define WS_TOTAL (608 + 3*NB*NG*KTOP*4)

__device__ __forceinline__ float sigm(float x) { return 1.0f / (1.0f + __expf(-x)); }

// focal_bce with t=0: ce*0.75*p^2
__device__ __forceinline__ float focal0(float x) {
    float p  = sigm(x);
    float ce = fmaxf(x, 0.0f) + __logf(1.0f + __expf(-fabsf(x)));
    return ce * 0.75f * p * p;
}

__device__ __forceinline__ float focal_t(float x, float t) {
    float p  = sigm(x);
    float ce = fmaxf(x, 0.0f) - x * t + __logf(1.0f + __expf(-fabsf(x)));
    float pt = p * t + (1.0f - p) * (1.0f - t);
    float at = 0.25f * t + 0.75f * (1.0f - t);
    float om = 1.0f - pt;
    return ce * at * om * om;
}

// ---------------- pass 1: any_pos[b] per level ----------------
__global__ void k_anypos(const float* __restrict__ gtb, int* __restrict__ anyp,
                         int H, int W, float inv_s) {
    int b  = blockIdx.y;
    int p  = blockIdx.x * blockDim.x + threadIdx.x;
    int HW = H * W;
    bool any = false;
    if (p < HW) {
        float cx = (float)(p % W) + 0.5f;
        float cy = (float)(p / W) + 0.5f;
        for (int g = 0; g < NG; ++g) {
            const float* bb = gtb + (b * NG + g) * 4;
            float x1 = bb[0] * inv_s, y1 = bb[1] * inv_s;
            float x2 = bb[2] * inv_s, y2 = bb[3] * inv_s;
            float gcx = (x1 + x2) * 0.5f, gcy = (y1 + y2) * 0.5f;
            bool m = (cx - x1 > 0.0f) && (cy - y1 > 0.0f) &&
                     (x2 - cx > 0.0f) && (y2 - cy > 0.0f) &&
                     (cx >= gcx - RAD) && (cx <= gcx + RAD) &&
                     (cy >= gcy - RAD) && (cy <= gcy + RAD);
            any = any || m;
        }
    }
    if (__any(any) && (threadIdx.x & 63) == 0) atomicOr(anyp + b, 1);
}

// ---------------- pass 2: top-10 fallback (rarely taken) ----------------
__global__ void k_fallback(const float* __restrict__ gtb, const int* __restrict__ anyp,
                           int* __restrict__ fb, int H, int W, float inv_s) {
    int b = blockIdx.x;
    if (anyp[b]) return;
    int g = threadIdx.x;
    if (g >= NG) return;
    const float* bb = gtb + (b * NG + g) * 4;
    float gcx = (bb[0] * inv_s + bb[2] * inv_s) * 0.5f;
    float gcy = (bb[1] * inv_s + bb[3] * inv_s) * 0.5f;
    float bd[KTOP];
    int   bi[KTOP];
    for (int t = 0; t < KTOP; ++t) { bd[t] = 3.0e38f; bi[t] = 0; }
    int HW = H * W;
    for (int p = 0; p < HW; ++p) {
        float cx = (float)(p % W) + 0.5f;
        float cy = (float)(p / W) + 0.5f;
        float dx = cx - gcx, dy = cy - gcy;
        float d = dx * dx + dy * dy;     // monotonic in sqrt-dist; stable ties by index
        if (d < bd[KTOP - 1]) {
            int t = KTOP - 1;
            while (t > 0 && d < bd[t - 1]) { bd[t] = bd[t - 1]; bi[t] = bi[t - 1]; --t; }
            bd[t] = d; bi[t] = p;
        }
    }
    int* o = fb + (b * NG + g) * KTOP;
    for (int t = 0; t < KTOP; ++t) o[t] = bi[t];
}

// ---------------- pass 3: the main per-point loss ----------------
__global__ __launch_bounds__(256) void k_main(
    const float* __restrict__ regp, const float* __restrict__ clsp,
    const float* __restrict__ gtb,  const int* __restrict__ lab,
    const int* __restrict__ anyp,   const int* __restrict__ fb,
    float* __restrict__ acc, float* __restrict__ npos, float* __restrict__ dfln,
    int H, int W, float inv_s)
{
    int b  = blockIdx.y;
    int p  = blockIdx.x * blockDim.x + threadIdx.x;
    int HW = H * W;
    bool valid = p < HW;
    int pc = valid ? p : 0;
    int i = pc / W, j = pc % W;
    float cx = (float)j + 0.5f, cy = (float)i + 0.5f;

    int base_r = (b * 4 * BINS) * HW + pc;   // reg[b, c, i, j], stride HW per channel
    int base_c = (b * NCLS) * HW + pc;

    // 4x softmax stats: expectation d and logZ
    float dv[4], lz[4];
#pragma unroll
    for (int k = 0; k < 4; ++k) {
        float x[BINS];
#pragma unroll
        for (int t = 0; t < BINS; ++t) x[t] = regp[base_r + (k * BINS + t) * HW];
        float m = x[0];
#pragma unroll
        for (int t = 1; t < BINS; ++t) m = fmaxf(m, x[t]);
        float s = 0.0f, e = 0.0f;
#pragma unroll
        for (int t = 0; t < BINS; ++t) {
            float ee = __expf(x[t] - m);
            s += ee; e += ee * (float)t;
        }
        dv[k] = e / s;
        lz[k] = __logf(s) + m;
    }
    float px1 = cx - dv[0], py1 = cy - dv[1];
    float px2 = cx + dv[2], py2 = cy + dv[3];
    float pa = (px2 - px1) * (py2 - py1);

    // focal-BCE(t=0) sum over classes
    float fzs = 0.0f;
    for (int c = 0; c < NCLS; ++c) {
        float xv = clsp[base_c + c * HW];
        fzs += focal0(xv);
    }

    bool anyb = anyp[b] != 0;
    float bxa = 0.0f, cla = 0.0f, dfa = 0.0f;
    float np = 0.0f;
    bool pospt = false;

    for (int g = 0; g < NG; ++g) {
        const float* bb = gtb + (b * NG + g) * 4;
        float x1 = bb[0] * inv_s, y1 = bb[1] * inv_s;
        float x2 = bb[2] * inv_s, y2 = bb[3] * inv_s;
        float dl = cx - x1, dt = cy - y1, dr = x2 - cx, db = y2 - cy;
        bool msk;
        if (anyb) {
            float gcx = (x1 + x2) * 0.5f, gcy = (y1 + y2) * 0.5f;
            msk = (dl > 0.0f) && (dt > 0.0f) && (dr > 0.0f) && (db > 0.0f) &&
                  (cx >= gcx - RAD) && (cx <= gcx + RAD) &&
                  (cy >= gcy - RAD) && (cy <= gcy + RAD);
        } else {
            msk = false;
            const int* fbp = fb + (b * NG + g) * KTOP;
#pragma unroll
            for (int t = 0; t < KTOP; ++t) msk = msk || (fbp[t] == pc);
        }
        msk = msk && valid;
        if (msk) {
            pospt = true;
            np += 1.0f;
            // IoU (pred vs gt)
            float ix1 = fmaxf(px1, x1), iy1 = fmaxf(py1, y1);
            float ix2 = fminf(px2, x2), iy2 = fminf(py2, y2);
            float iw = fmaxf(ix2 - ix1, 0.0f), ih = fmaxf(iy2 - iy1, 0.0f);
            float inter = iw * ih;
            float ga = (x2 - x1) * (y2 - y1);
            float iou = inter / (pa + ga - inter + 1e-6f);
            bxa += 1.0f - iou;
            // DFL
            float ltrb[4] = { dl, dt, dr, db };
#pragma unroll
            for (int k = 0; k < 4; ++k) {
                float t  = fminf(fmaxf(ltrb[k], 0.0f), 15.9999f);
                float lf = floorf(t);
                int   lb = (int)lf;
                int   rb = lb + 1 > REGMAX ? REGMAX : lb + 1;
                float wl = (float)rb - t, wr = t - lf;
                float xl = regp[base_r + (k * BINS + lb) * HW];
                float xr = regp[base_r + (k * BINS + rb) * HW];
                dfa -= (xl - lz[k]) * wl + (xr - lz[k]) * wr;
            }
            // cls positive term
            int   c   = lab[b * NG + g];
            float xat = clsp[base_c + c * HW];
            cla += fzs - focal0(xat) + focal_t(xat, iou);
        }
    }
    if (valid && !pospt) cla += fzs;   // cls_neg

    // block reduction (4 waves of 64)
    float v0 = bxa, v1 = cla, v2 = dfa, v3 = np;
    for (int off = 32; off > 0; off >>= 1) {
        v0 += __shfl_down(v0, off);
        v1 += __shfl_down(v1, off);
        v2 += __shfl_down(v2, off);
        v3 += __shfl_down(v3, off);
    }
    __shared__ float red[4][4];
    int wid = threadIdx.x >> 6, lane = threadIdx.x & 63;
    if (lane == 0) {
        red[wid][0] = v0; red[wid][1] = v1; red[wid][2] = v2; red[wid][3] = v3;
    }
    __syncthreads();
    if (threadIdx.x == 0) {
        float s0 = 0, s1 = 0, s2 = 0, s3 = 0;
        int nw = (blockDim.x + 63) >> 6;
        for (int w = 0; w < nw; ++w) {
            s0 += red[w][0]; s1 += red[w][1]; s2 += red[w][2]; s3 += red[w][3];
        }
        atomicAdd(&acc[0], s0);
        atomicAdd(&acc[1], s1);
        atomicAdd(&dfln[b], s2);
        atomicAdd(&npos[b], s3);
    }
}

// ---------------- pass 4: combine ----------------
__global__ void k_final(const float* __restrict__ acc, const float* __restrict__ npos,
                        const float* __restrict__ dfln, float* __restrict__ out) {
    float tb = acc[0], tc = acc[1], td = 0.0f;
    for (int i = 0; i < 3 * NB; ++i) {
        float n = npos[i];
        if (n > 0.0f) td += dfln[i] / (n * 4.0f);
    }
    out[0] = 7.5f * tb + 1.0f * tc + 1.5f * td;
    out[1] = tb;
    out[2] = tc;
    out[3] = td;
}

extern "C" void kernel_launch(void* const* d_in, const int* in_sizes, int n_in,
                              void* d_out, int out_size, void* d_ws, size_t ws_size,
                              hipStream_t stream) {
    const float* reg0 = (const float*)d_in[0];
    const float* cls0 = (const float*)d_in[1];
    const float* reg1 = (const float*)d_in[2];
    const float* cls1 = (const float*)d_in[3];
    const float* reg2 = (const float*)d_in[4];
    const float* cls2 = (const float*)d_in[5];
    const float* gtb  = (const float*)d_in[6];
    const int*   lab  = (const int*)d_in[7];
    float* out = (float*)d_out;

    char*  ws   = (char*)d_ws;
    float* acc  = (float*)(ws + WS_ACC);
    float* npos = (float*)(ws + WS_NPOS);
    float* dfln = (float*)(ws + WS_DFLN);
    int*   anyp = (int*)(ws + WS_ANYP);
    int*   fb   = (int*)(ws + WS_FB);

    hipMemsetAsync(d_ws, 0, WS_TOTAL, stream);

    struct Lv { const float* r; const float* c; int H; int W; float inv_s; };
    Lv lv[3] = { { reg0, cls0, 80, 80, 1.0f / 8.0f },
                 { reg1, cls1, 40, 40, 1.0f / 16.0f },
                 { reg2, cls2, 20, 20, 1.0f / 32.0f } };

    for (int l = 0; l < 3; ++l) {
        int H = lv[l].H, W = lv[l].W, HW = H * W;
        dim3 grid((HW + 255) / 256, NB);
        k_anypos<<<grid, 256, 0, stream>>>(gtb, anyp + l * NB, H, W, lv[l].inv_s);
        k_fallback<<<NB, 64, 0, stream>>>(gtb, anyp + l * NB,
                                          fb + l * NB * NG * KTOP, H, W, lv[l].inv_s);
        k_main<<<grid, 256, 0, stream>>>(lv[l].r, lv[l].c, gtb, lab,
                                         anyp + l * NB, fb + l * NB * NG * KTOP,
                                         acc, npos + l * NB, dfln + l * NB,
                                         H, W, lv[l].inv_s);
    }
    k_final<<<1, 1, 0, stream>>>(acc, npos, dfln, out);
}